// Round 16
// baseline (194.075 us; speedup 1.0000x reference)
//
#include <hip/hip_runtime.h>
#include <hip/hip_bf16.h>
#include <stdint.h>

typedef __hip_bfloat16 bf16;
typedef __attribute__((ext_vector_type(8))) short short8;    // 8 bf16 (4 VGPRs) MFMA A/B frag
typedef __attribute__((ext_vector_type(4))) float f32x4;     // 16x16 C/D frag
typedef __attribute__((ext_vector_type(16))) float f32x16;   // 32x32 C/D frag

#define MFMA16(a, b, c) __builtin_amdgcn_mfma_f32_16x16x32_bf16((a), (b), (c), 0, 0, 0)
#define MFMA32(a, b, c) __builtin_amdgcn_mfma_f32_32x32x16_bf16((a), (b), (c), 0, 0, 0)

__device__ __forceinline__ unsigned short f2bf(float f) {
  bf16 h = __float2bfloat16(f);
  unsigned short u;
  __builtin_memcpy(&u, &h, 2);
  return u;
}

__device__ __forceinline__ float bf2f(unsigned short u) {
  uint32_t x = ((uint32_t)u) << 16;
  float f;
  __builtin_memcpy(&f, &x, 4);
  return f;
}

__device__ __forceinline__ uint32_t cvtpk(float lo, float hi) {
  uint32_t r;
  asm("v_cvt_pk_bf16_f32 %0, %1, %2" : "=v"(r) : "v"(lo), "v"(hi));
  return r;
}

// v_permlane32_swap_b32 a, b : a.lanes[32:63] <-> b.lanes[0:31]
__device__ __forceinline__ void pl32swap(uint32_t& a, uint32_t& b) {
  asm volatile("v_permlane32_swap_b32 %0, %1" : "+v"(a), "+v"(b));
}

__device__ __forceinline__ void gload_lds16(const void* g, void* l) {
  __builtin_amdgcn_global_load_lds(
      (const __attribute__((address_space(1))) uint32_t*)g,
      (__attribute__((address_space(3))) uint32_t*)l, 16, 0, 0);
}

// 128B-row XOR swizzle: 16B chunk c of row r lives at chunk (c ^ (r & 7)).
__device__ __forceinline__ int swz_chunk(int row, int c) { return c ^ (row & 7); }

// ---------------------------------------------------------------- convert ----
__global__ __launch_bounds__(256) void cvt_all(
    const float* __restrict__ x,
    const float* __restrict__ w0, const float* __restrict__ w1,
    const float* __restrict__ w2, const float* __restrict__ w3,
    bf16* __restrict__ xo,
    bf16* __restrict__ o0, bf16* __restrict__ o1,
    bf16* __restrict__ o2, bf16* __restrict__ o3) {
  int idx = blockIdx.x * 256 + threadIdx.x;     // 0..2162687
  const float* src;
  bf16* dst;
  int i;
  if (idx < 1572864) {
    src = x; dst = xo; i = idx;
  } else {
    int r = idx - 1572864;
    int w = r / 147456;
    i = r - w * 147456;
    src = (w == 0) ? w0 : (w == 1) ? w1 : (w == 2) ? w2 : w3;
    dst = (w == 0) ? o0 : (w == 1) ? o1 : (w == 2) ? o2 : o3;
  }
  float4 v = ((const float4*)src)[i];
  ushort4 u;
  u.x = f2bf(v.x); u.y = f2bf(v.y); u.z = f2bf(v.z); u.w = f2bf(v.w);
  ((ushort4*)dst)[i] = u;
}

// --------------------------------------------------------- fused QKV GEMM ----
__global__ __launch_bounds__(256, 4) void gemm_qkv(
    const bf16* __restrict__ A,
    const bf16* __restrict__ Wqb, const bf16* __restrict__ Wkb,
    const bf16* __restrict__ Wvb,
    const float* __restrict__ bq, const float* __restrict__ bk,
    const float* __restrict__ bv,
    bf16* __restrict__ Qh, bf16* __restrict__ Kh, bf16* __restrict__ Vtt,
    float sq) {
  __shared__ bf16 As[128 * 64];   // 16KB, swizzled
  __shared__ bf16 Bs[128 * 64];
  const int tid = threadIdx.x;
  const int lane = tid & 63, wid = tid >> 6;
  const int wr = wid >> 1, wc = wid & 1;
  const int l15 = lane & 15, lhi = lane >> 4;
  const int tm = blockIdx.x * 128;
  const int by = blockIdx.y;
  const int seg = by / 6;                 // 0=Q 1=K 2=V
  const int tn = (by - seg * 6) * 128;

  const bf16* B = (seg == 0) ? Wqb : (seg == 1) ? Wkb : Wvb;
  const float* bias = (seg == 0) ? bq : (seg == 1) ? bk : bv;
  const float scale = (seg == 0) ? sq : 1.0f;
  const int K = 768;

  f32x4 zero = {0.f, 0.f, 0.f, 0.f};
  f32x4 acc[4][4];
  for (int i = 0; i < 4; ++i)
    for (int j = 0; j < 4; ++j) acc[i][j] = zero;

  for (int k0 = 0; k0 < K; k0 += 64) {
    __syncthreads();
    for (int it = 0; it < 4; ++it) {
      int o = (tid + it * 256) << 4;              // 0..16K-16
      int row = o >> 7, c = (o >> 4) & 7;
      int sw = swz_chunk(row, c) << 4;            // pre-swizzled source chunk
      gload_lds16((const char*)A + (((size_t)(tm + row) * K + k0) << 1) + sw, (char*)As + o);
      gload_lds16((const char*)B + (((size_t)(tn + row) * K + k0) << 1) + sw, (char*)Bs + o);
    }
    __syncthreads();
    for (int ks = 0; ks < 2; ++ks) {
      short8 af[4], bfr[4];
      for (int mi = 0; mi < 4; ++mi) {
        int row = wr * 64 + mi * 16 + l15;
        af[mi] = *(const short8*)((const char*)As + row * 128 +
                                  (swz_chunk(row, ks * 4 + lhi) << 4));
      }
      for (int ni = 0; ni < 4; ++ni) {
        int row = wc * 64 + ni * 16 + l15;
        bfr[ni] = *(const short8*)((const char*)Bs + row * 128 +
                                   (swz_chunk(row, ks * 4 + lhi) << 4));
      }
      for (int mi = 0; mi < 4; ++mi)
        for (int ni = 0; ni < 4; ++ni)
          acc[mi][ni] = MFMA16(af[mi], bfr[ni], acc[mi][ni]);
    }
  }

  if (seg == 2) {
    for (int mi = 0; mi < 4; ++mi)
      for (int ni = 0; ni < 4; ++ni) {
        int m0 = tm + wr * 64 + mi * 16 + lhi * 4;     // tokens m0..m0+3
        int n = tn + wc * 64 + ni * 16 + l15;
        int b = m0 >> 12, s = m0 & 4095, hh = n >> 6, d = n & 63;
        float bia = bias[n];
        ushort4 us;
        us.x = f2bf(acc[mi][ni][0] + bia);
        us.y = f2bf(acc[mi][ni][1] + bia);
        us.z = f2bf(acc[mi][ni][2] + bia);
        us.w = f2bf(acc[mi][ni][3] + bia);
        size_t e = (size_t)(b * 12 + hh) * 262144 + (size_t)(s >> 6) * 4096 +
                   (size_t)((s >> 3) & 7) * 512 + d * 8 + (s & 7);
        *(ushort4*)(Vtt + e) = us;
      }
  } else {
    bf16* dst = (seg == 0) ? Qh : Kh;
    for (int mi = 0; mi < 4; ++mi)
      for (int ni = 0; ni < 4; ++ni)
        for (int j = 0; j < 4; ++j) {
          int m = tm + wr * 64 + mi * 16 + lhi * 4 + j;
          int n = tn + wc * 64 + ni * 16 + l15;
          float v = (acc[mi][ni][j] + bias[n]) * scale;
          int b = m >> 12, s = m & 4095, hh = n >> 6, d = n & 63;
          dst[(((size_t)(b * 12 + hh) * 4096 + s) << 6) + d] = __float2bfloat16(v);
        }
  }
}

// ------------------------------------------------------------ out-proj GEMM --
__global__ __launch_bounds__(256, 4) void gemm_wo(
    const bf16* __restrict__ A, const bf16* __restrict__ B,
    const float* __restrict__ bias, float* __restrict__ C) {
  __shared__ bf16 As[128 * 64];   // 16KB
  __shared__ bf16 Bs[64 * 64];    // 8KB
  const int tid = threadIdx.x;
  const int lane = tid & 63, wid = tid >> 6;
  const int l15 = lane & 15, lhi = lane >> 4;
  const int tm = blockIdx.x * 128, tn = blockIdx.y * 64;
  const int K = 768;

  f32x4 zero = {0.f, 0.f, 0.f, 0.f};
  f32x4 acc[2][4];
  for (int i = 0; i < 2; ++i)
    for (int j = 0; j < 4; ++j) acc[i][j] = zero;

  for (int k0 = 0; k0 < K; k0 += 64) {
    __syncthreads();
    for (int it = 0; it < 4; ++it) {
      int o = (tid + it * 256) << 4;
      int row = o >> 7, c = (o >> 4) & 7;
      int sw = swz_chunk(row, c) << 4;
      gload_lds16((const char*)A + (((size_t)(tm + row) * K + k0) << 1) + sw, (char*)As + o);
    }
    for (int it = 0; it < 2; ++it) {
      int o = (tid + it * 256) << 4;              // 0..8K-16
      int row = o >> 7, c = (o >> 4) & 7;
      int sw = swz_chunk(row, c) << 4;
      gload_lds16((const char*)B + (((size_t)(tn + row) * K + k0) << 1) + sw, (char*)Bs + o);
    }
    __syncthreads();
    for (int ks = 0; ks < 2; ++ks) {
      short8 af[2], bfr[4];
      for (int mi = 0; mi < 2; ++mi) {
        int row = wid * 32 + mi * 16 + l15;
        af[mi] = *(const short8*)((const char*)As + row * 128 +
                                  (swz_chunk(row, ks * 4 + lhi) << 4));
      }
      for (int ni = 0; ni < 4; ++ni) {
        int row = ni * 16 + l15;
        bfr[ni] = *(const short8*)((const char*)Bs + row * 128 +
                                   (swz_chunk(row, ks * 4 + lhi) << 4));
      }
      for (int mi = 0; mi < 2; ++mi)
        for (int ni = 0; ni < 4; ++ni)
          acc[mi][ni] = MFMA16(af[mi], bfr[ni], acc[mi][ni]);
    }
  }

  for (int mi = 0; mi < 2; ++mi)
    for (int ni = 0; ni < 4; ++ni)
      for (int j = 0; j < 4; ++j) {
        int m = tm + wid * 32 + mi * 16 + lhi * 4 + j;
        int n = tn + ni * 16 + l15;
        C[(size_t)m * 768 + n] = acc[mi][ni][j] + bias[n];
      }
}

// --------------------------------------------------------------- attention ---
// 4-deep LDS buffering, ONE BARRIER PER 2 TILES: round r stages tiles
// 2r+2,2r+3 and processes 2r,2r+1 with no intra-round sync -> waves drift,
// so one wave's exp (VALU) overlaps another's QK/PV (matrix pipe).
// Hazard: buf[(2r+2)&3] last read at tile 2r-2 (round r-1), protected by the
// round r-1 end barrier (compiler emits vmcnt(0) drain there).
// LDS 64KB (4K + 4V bufs) -> 2 blocks/CU; SPLIT=1 grid 1536 = 3 exact
// residency rounds. SPLIT=1 writes unnormalized partials + psum; combine
// kernel normalizes (path verified in round 15).
template <int SPLIT>
__global__ __launch_bounds__(256, 2) void attn_kernel(
    const bf16* __restrict__ Qh, const bf16* __restrict__ Kh,
    const bf16* __restrict__ VTT, bf16* __restrict__ AO,
    bf16* __restrict__ OP0, bf16* __restrict__ OP1,
    float* __restrict__ PS0, float* __restrict__ PS1) {
  __shared__ float4 smem4[65536 / 16];   // K bufs 0..32K | V bufs 32K..64K
  char* smraw = (char*)smem4;
#define KB4(b) (smraw + (b) * 8192)
#define VB4(b) (smraw + 32768 + (b) * 8192)
  float* OX = (float*)smraw;             // [2 qsub][64 lane][68] (epilogue)

  const int tid = threadIdx.x;
  const int lane = tid & 63, wid = tid >> 6;
  const int l31 = lane & 31, h = lane >> 5;
  const int qsub = wid & 1, kvh = wid >> 1;

  // bijective XCD swizzle: all blocks of a head on one XCD
  const int i = blockIdx.x;
  const int xcd = i & 7, slot = i >> 3;
  int bh, qt, kvp;
  if (SPLIT) {
    bh = xcd * 3 + (slot >> 6);          // slot 0..191
    int r = slot & 63;
    qt = r >> 1;
    kvp = r & 1;
  } else {
    bh = xcd * 3 + (slot >> 5);          // slot 0..95
    qt = slot & 31;
    kvp = 0;
  }
  const int NT = SPLIT ? 32 : 64;
  const int kv0 = kvp * 32;

  const size_t hb = (size_t)bh * 262144;       // 4096*64 elements per head
  const bf16* Qb = Qh + hb;
  const bf16* Kb = Kh + hb;
  const char* Vbc = (const char*)(VTT + hb);   // VT tile kt at +kt*8192 B
  const int qb = qt * 128 + qsub * 64;

  short8 qf[2][4];
#pragma unroll
  for (int j = 0; j < 2; ++j)
#pragma unroll
    for (int ki = 0; ki < 4; ++ki)
      qf[j][ki] = *(const short8*)((const char*)Qb + (size_t)(qb + 32 * j + l31) * 128 +
                                   ki * 32 + h * 16);

  f32x16 z16;
  for (int i2 = 0; i2 < 16; ++i2) z16[i2] = 0.f;
  f32x16 o00 = z16, o01 = z16, o10 = z16, o11 = z16;
  float psum0 = 0.f, psum1 = 0.f;

  const int krow = kvh * 32 + l31;

#define STAGE(akt, b)                                                      \
  for (int it = 0; it < 2; ++it) {                                         \
    int o = (tid + it * 256) << 4;                                         \
    int row = o >> 7, c = (o >> 4) & 7;                                    \
    gload_lds16((const char*)Kb + (size_t)(akt) * 8192 + row * 128 +       \
                    (swz_chunk(row, c) << 4), KB4(b) + o);                 \
    gload_lds16(Vbc + (size_t)(akt) * 8192 + (swz_chunk(row, c) << 10) +   \
                    (row << 4), VB4(b) + o);                               \
  }

#define PROCESS(b)                                                         \
  {                                                                        \
    const char* Kl = KB4(b);                                               \
    const char* Vl = VB4(b);                                               \
    f32x16 s0, s1;                                                         \
    __builtin_amdgcn_s_setprio(1);                                         \
    {                                                                      \
      short8 kf = *(const short8*)(Kl + krow * 128 + (swz_chunk(krow, h) << 4)); \
      s0 = MFMA32(kf, qf[0][0], z16);                                      \
      s1 = MFMA32(kf, qf[1][0], z16);                                      \
    }                                                                      \
    _Pragma("unroll")                                                      \
    for (int ki = 1; ki < 4; ++ki) {                                       \
      short8 kf = *(const short8*)(Kl + krow * 128 +                       \
                                   (swz_chunk(krow, 2 * ki + h) << 4));    \
      s0 = MFMA32(kf, qf[0][ki], s0);                                      \
      s1 = MFMA32(kf, qf[1][ki], s1);                                      \
    }                                                                      \
    __builtin_amdgcn_s_setprio(0);                                         \
    short8 pb[2][2];                                                       \
    _Pragma("unroll")                                                      \
    for (int j = 0; j < 2; ++j) {                                          \
      _Pragma("unroll")                                                    \
      for (int kk = 0; kk < 2; ++kk) {                                     \
        float p[8];                                                        \
        _Pragma("unroll")                                                  \
        for (int e = 0; e < 8; ++e)                                        \
          p[e] = __builtin_amdgcn_exp2f(j ? s1[8 * kk + e] : s0[8 * kk + e]); \
        float ps = ((p[0] + p[1]) + (p[2] + p[3])) + ((p[4] + p[5]) + (p[6] + p[7])); \
        if (j) psum1 += ps; else psum0 += ps;                              \
        uint32_t A0 = cvtpk(p[0], p[1]), A1 = cvtpk(p[2], p[3]);           \
        uint32_t B0 = cvtpk(p[4], p[5]), B1 = cvtpk(p[6], p[7]);           \
        pl32swap(A0, B0);                                                  \
        pl32swap(A1, B1);                                                  \
        uint32_t w_[4] = {A0, A1, B0, B1};                                 \
        short8 frag;                                                       \
        __builtin_memcpy(&frag, w_, 16);                                   \
        pb[j][kk] = frag;                                                  \
      }                                                                    \
    }                                                                      \
    __builtin_amdgcn_s_setprio(1);                                         \
    _Pragma("unroll")                                                      \
    for (int kk = 0; kk < 2; ++kk) {                                       \
      short8 v0 = *(const short8*)(Vl + l31 * 128 +                        \
                                   (swz_chunk(l31, 4 * kvh + 2 * kk + h) << 4)); \
      short8 v1 = *(const short8*)(Vl + (32 + l31) * 128 +                 \
                                   (swz_chunk(32 + l31, 4 * kvh + 2 * kk + h) << 4)); \
      o00 = MFMA32(v0, pb[0][kk], o00);                                    \
      o01 = MFMA32(v0, pb[1][kk], o01);                                    \
      o10 = MFMA32(v1, pb[0][kk], o10);                                    \
      o11 = MFMA32(v1, pb[1][kk], o11);                                    \
    }                                                                      \
    __builtin_amdgcn_s_setprio(0);                                         \
  }

  // prologue: stage tiles 0,1 into bufs 0,1
  STAGE(kv0 + 0, 0);
  STAGE(kv0 + 1, 1);
  __syncthreads();

  for (int r = 0; r < NT / 2; ++r) {
    int t0 = 2 * r;
    if (r < NT / 2 - 1) {
      STAGE(kv0 + t0 + 2, (t0 + 2) & 3);
      STAGE(kv0 + t0 + 3, (t0 + 3) & 3);
    }
    PROCESS(t0 & 3);
    PROCESS((t0 + 1) & 3);
    __syncthreads();
  }
#undef STAGE
#undef PROCESS

  psum0 += __shfl_xor(psum0, 32);
  psum1 += __shfl_xor(psum1, 32);

  float* W = OX + (size_t)(qsub * 64 + lane) * 68;
  if (kvh == 1) {
#pragma unroll
    for (int g = 0; g < 4; ++g) {
      *(float4*)(W + 0 * 16 + 4 * g) = make_float4(o00[4*g], o00[4*g+1], o00[4*g+2], o00[4*g+3]);
      *(float4*)(W + 1 * 16 + 4 * g) = make_float4(o01[4*g], o01[4*g+1], o01[4*g+2], o01[4*g+3]);
      *(float4*)(W + 2 * 16 + 4 * g) = make_float4(o10[4*g], o10[4*g+1], o10[4*g+2], o10[4*g+3]);
      *(float4*)(W + 3 * 16 + 4 * g) = make_float4(o11[4*g], o11[4*g+1], o11[4*g+2], o11[4*g+3]);
    }
    W[64] = psum0;
    W[65] = psum1;
  }
  __syncthreads();
  if (kvh == 0) {
#pragma unroll
    for (int g = 0; g < 4; ++g) {
      float4 a0 = *(const float4*)(W + 0 * 16 + 4 * g);
      float4 a1 = *(const float4*)(W + 1 * 16 + 4 * g);
      float4 a2 = *(const float4*)(W + 2 * 16 + 4 * g);
      float4 a3 = *(const float4*)(W + 3 * 16 + 4 * g);
      o00[4*g] += a0.x; o00[4*g+1] += a0.y; o00[4*g+2] += a0.z; o00[4*g+3] += a0.w;
      o01[4*g] += a1.x; o01[4*g+1] += a1.y; o01[4*g+2] += a1.z; o01[4*g+3] += a1.w;
      o10[4*g] += a2.x; o10[4*g+1] += a2.y; o10[4*g+2] += a2.z; o10[4*g+3] += a2.w;
      o11[4*g] += a3.x; o11[4*g+1] += a3.y; o11[4*g+2] += a3.z; o11[4*g+3] += a3.w;
    }
    psum0 += W[64];
    psum1 += W[65];

    const int b = bh / 12, hd = bh % 12;
    if (SPLIT) {
      bf16* OPp = kvp ? OP1 : OP0;
      float* PSp = kvp ? PS1 : PS0;
#pragma unroll
      for (int j = 0; j < 2; ++j) {
        int q = qb + 32 * j + l31;
        char* base = (char*)OPp + (((size_t)(b * 4096 + q)) * 768 + hd * 64) * 2;
#pragma unroll
        for (int t = 0; t < 2; ++t) {
#pragma unroll
          for (int u = 0; u < 4; ++u) {
            ushort4 us;
            float v0 = (t ? (j ? o11[4*u+0] : o10[4*u+0]) : (j ? o01[4*u+0] : o00[4*u+0]));
            float v1 = (t ? (j ? o11[4*u+1] : o10[4*u+1]) : (j ? o01[4*u+1] : o00[4*u+1]));
            float v2 = (t ? (j ? o11[4*u+2] : o10[4*u+2]) : (j ? o01[4*u+2] : o00[4*u+2]));
            float v3 = (t ? (j ? o11[4*u+3] : o10[4*u+3]) : (j ? o01[4*u+3] : o00[4*u+3]));
            us.x = f2bf(v0); us.y = f2bf(v1); us.z = f2bf(v2); us.w = f2bf(v3);
            int d0 = 32 * t + 8 * u + 4 * h;
            *(ushort4*)(base + d0 * 2) = us;
          }
        }
        PSp[(size_t)bh * 4096 + q] = j ? psum1 : psum0;
      }
    } else {
      float pinv0 = 1.0f / psum0;
      float pinv1 = 1.0f / psum1;
#pragma unroll
      for (int j = 0; j < 2; ++j) {
        int q = qb + 32 * j + l31;
        char* base = (char*)AO + (((size_t)(b * 4096 + q)) * 768 + hd * 64) * 2;
        float pv = j ? pinv1 : pinv0;
#pragma unroll
        for (int t = 0; t < 2; ++t) {
#pragma unroll
          for (int u = 0; u < 4; ++u) {
            ushort4 us;
            float v0 = (t ? (j ? o11[4*u+0] : o10[4*u+0]) : (j ? o01[4*u+0] : o00[4*u+0]));
            float v1 = (t ? (j ? o11[4*u+1] : o10[4*u+1]) : (j ? o01[4*u+1] : o00[4*u+1]));
            float v2 = (t ? (j ? o11[4*u+2] : o10[4*u+2]) : (j ? o01[4*u+2] : o00[4*u+2]));
            float v3 = (t ? (j ? o11[4*u+3] : o10[4*u+3]) : (j ? o01[4*u+3] : o00[4*u+3]));
            us.x = f2bf(v0 * pv); us.y = f2bf(v1 * pv);
            us.z = f2bf(v2 * pv); us.w = f2bf(v3 * pv);
            int d0 = 32 * t + 8 * u + 4 * h;
            *(ushort4*)(base + d0 * 2) = us;
          }
        }
      }
    }
  }
#undef KB4
#undef VB4
}

// ------------------------------------------------------- kv-split combine ---
__global__ __launch_bounds__(256) void combine_kernel(
    const bf16* __restrict__ OP0, const bf16* __restrict__ OP1,
    const float* __restrict__ PS0, const float* __restrict__ PS1,
    bf16* __restrict__ AO) {
  int t = blockIdx.x * 256 + threadIdx.x;   // 0..786431
  size_t e0 = (size_t)t * 8;
  int row = (int)(e0 / 768);                // b*4096 + q
  int col = (int)(e0 - (size_t)row * 768);  // hd*64 + d0
  int hd = col >> 6;
  int bh = (row >> 12) * 12 + hd;
  int q = row & 4095;
  float r = 1.0f / (PS0[(size_t)bh * 4096 + q] + PS1[(size_t)bh * 4096 + q]);
  ushort4 a0 = *(const ushort4*)(OP0 + e0);
  ushort4 a1 = *(const ushort4*)(OP0 + e0 + 4);
  ushort4 b0 = *(const ushort4*)(OP1 + e0);
  ushort4 b1 = *(const ushort4*)(OP1 + e0 + 4);
  ushort4 o0, o1;
  o0.x = f2bf((bf2f(a0.x) + bf2f(b0.x)) * r);
  o0.y = f2bf((bf2f(a0.y) + bf2f(b0.y)) * r);
  o0.z = f2bf((bf2f(a0.z) + bf2f(b0.z)) * r);
  o0.w = f2bf((bf2f(a0.w) + bf2f(b0.w)) * r);
  o1.x = f2bf((bf2f(a1.x) + bf2f(b1.x)) * r);
  o1.y = f2bf((bf2f(a1.y) + bf2f(b1.y)) * r);
  o1.z = f2bf((bf2f(a1.z) + bf2f(b1.z)) * r);
  o1.w = f2bf((bf2f(a1.w) + bf2f(b1.w)) * r);
  *(ushort4*)(AO + e0) = o0;
  *(ushort4*)(AO + e0 + 4) = o1;
}

// ------------------------------------------------------------------ launch ---
extern "C" void kernel_launch(void* const* d_in, const int* in_sizes, int n_in,
                              void* d_out, int out_size, void* d_ws, size_t ws_size,
                              hipStream_t stream) {
  (void)in_sizes; (void)n_in; (void)out_size;
  const float* x  = (const float*)d_in[0];
  const float* Wq = (const float*)d_in[1];
  const float* bq = (const float*)d_in[2];
  const float* Wk = (const float*)d_in[3];
  const float* bk = (const float*)d_in[4];
  const float* Wv = (const float*)d_in[5];
  const float* bv = (const float*)d_in[6];
  const float* Wo = (const float*)d_in[7];
  const float* bo = (const float*)d_in[8];

  char* ws = (char*)d_ws;
  bf16* Qh  = (bf16*)(ws + 0);           // [24][4096][64]
  bf16* Kh  = (bf16*)(ws + 12582912);
  bf16* VTT = (bf16*)(ws + 25165824);    // tiled-VT [24][64][8][64][8]
  bf16* xb  = (bf16*)(ws + 37748736);    // x bf16; dead after gemm_qkv
  bf16* Wqb = (bf16*)(ws + 50331648);
  bf16* Wkb = (bf16*)(ws + 51511296);
  bf16* Wvb = (bf16*)(ws + 52690944);
  bf16* Wob = (bf16*)(ws + 53870592);    // ends 55050240
  bf16* OP0 = xb;                        // reuses dead xb (12.58MB)
  bf16* OP1 = (bf16*)(ws + 55050240);    // 12.58MB -> 67633152
  float* PS0 = (float*)(ws + 67633152);  // 393216B -> 68026368
  float* PS1 = (float*)(ws + 68026368);  // 393216B -> 68419584
  const size_t NEED = 68419584;

  cvt_all<<<8448, 256, 0, stream>>>(x, Wq, Wk, Wv, Wo, xb, Wqb, Wkb, Wvb, Wob);

  const float SQ = 0.125f * 1.4426950408889634f;  // 1/sqrt(64) * log2(e)
  dim3 gq(64, 18);
  gemm_qkv<<<gq, 256, 0, stream>>>(xb, Wqb, Wkb, Wvb, bq, bk, bv,
                                   Qh, Kh, VTT, SQ);
  dim3 gw(64, 12);
  if (ws_size >= NEED) {
    // kv-split x2, 4-deep bufs: 1536 blocks at 2/CU = 3 exact rounds
    attn_kernel<1><<<1536, 256, 0, stream>>>(Qh, Kh, VTT, nullptr,
                                             OP0, OP1, PS0, PS1);
    bf16* AOq = Qh;                      // Qh dead after attn
    combine_kernel<<<3072, 256, 0, stream>>>(OP0, OP1, PS0, PS1, AOq);
    gemm_wo<<<gw, 256, 0, stream>>>(AOq, Wob, bo, (float*)d_out);
  } else {
    // fallback: single-pass path
    bf16* AO = xb;
    attn_kernel<0><<<768, 256, 0, stream>>>(Qh, Kh, VTT, AO,
                                            nullptr, nullptr, nullptr, nullptr);
    gemm_wo<<<gw, 256, 0, stream>>>(AO, Wob, bo, (float*)d_out);
  }
}

// Round 17
// 180.074 us; speedup vs baseline: 1.0778x; 1.0778x over previous
//
#include <hip/hip_runtime.h>
#include <hip/hip_bf16.h>
#include <stdint.h>

typedef __hip_bfloat16 bf16;
typedef __attribute__((ext_vector_type(8))) short short8;    // 8 bf16 (4 VGPRs) MFMA A/B frag
typedef __attribute__((ext_vector_type(4))) float f32x4;     // 16x16 C/D frag
typedef __attribute__((ext_vector_type(16))) float f32x16;   // 32x32 C/D frag

#define MFMA16(a, b, c) __builtin_amdgcn_mfma_f32_16x16x32_bf16((a), (b), (c), 0, 0, 0)
#define MFMA32(a, b, c) __builtin_amdgcn_mfma_f32_32x32x16_bf16((a), (b), (c), 0, 0, 0)

__device__ __forceinline__ unsigned short f2bf(float f) {
  bf16 h = __float2bfloat16(f);
  unsigned short u;
  __builtin_memcpy(&u, &h, 2);
  return u;
}

__device__ __forceinline__ uint32_t cvtpk(float lo, float hi) {
  uint32_t r;
  asm("v_cvt_pk_bf16_f32 %0, %1, %2" : "=v"(r) : "v"(lo), "v"(hi));
  return r;
}

// v_permlane32_swap_b32 a, b : a.lanes[32:63] <-> b.lanes[0:31]
__device__ __forceinline__ void pl32swap(uint32_t& a, uint32_t& b) {
  asm volatile("v_permlane32_swap_b32 %0, %1" : "+v"(a), "+v"(b));
}

__device__ __forceinline__ void gload_lds16(const void* g, void* l) {
  __builtin_amdgcn_global_load_lds(
      (const __attribute__((address_space(1))) uint32_t*)g,
      (__attribute__((address_space(3))) uint32_t*)l, 16, 0, 0);
}

// 128B-row XOR swizzle: 16B chunk c of row r lives at chunk (c ^ (r & 7)).
__device__ __forceinline__ int swz_chunk(int row, int c) { return c ^ (row & 7); }

// ---------------------------------------------------------------- convert ----
// x (1572864 float4) + 4 weights (147456 float4 each) in ONE launch.
__global__ __launch_bounds__(256) void cvt_all(
    const float* __restrict__ x,
    const float* __restrict__ w0, const float* __restrict__ w1,
    const float* __restrict__ w2, const float* __restrict__ w3,
    bf16* __restrict__ xo,
    bf16* __restrict__ o0, bf16* __restrict__ o1,
    bf16* __restrict__ o2, bf16* __restrict__ o3) {
  int idx = blockIdx.x * 256 + threadIdx.x;     // 0..2162687
  const float* src;
  bf16* dst;
  int i;
  if (idx < 1572864) {
    src = x; dst = xo; i = idx;
  } else {
    int r = idx - 1572864;
    int w = r / 147456;
    i = r - w * 147456;
    src = (w == 0) ? w0 : (w == 1) ? w1 : (w == 2) ? w2 : w3;
    dst = (w == 0) ? o0 : (w == 1) ? o1 : (w == 2) ? o2 : o3;
  }
  float4 v = ((const float4*)src)[i];
  ushort4 u;
  u.x = f2bf(v.x); u.y = f2bf(v.y); u.z = f2bf(v.z); u.w = f2bf(v.w);
  ((ushort4*)dst)[i] = u;
}

// --------------------------------------------------------- fused QKV GEMM ----
// BK=64, XOR-swizzled LDS. blockIdx.y 0..17; y/6 selects {Q,K,V}.
// Q/K written bf16 head-split [(b*12+h)*4096+s][64] (Q pre-scaled).
// V written in tiled-VT layout: elem(bh, s, d) =
//   bh*262144 + (s>>6)*4096 + ((s>>3)&7)*512 + d*8 + (s&7)
// (16B chunk (kt, c', d) = tokens c'*8..+7 of dim d, contiguous).
__global__ __launch_bounds__(256, 4) void gemm_qkv(
    const bf16* __restrict__ A,
    const bf16* __restrict__ Wqb, const bf16* __restrict__ Wkb,
    const bf16* __restrict__ Wvb,
    const float* __restrict__ bq, const float* __restrict__ bk,
    const float* __restrict__ bv,
    bf16* __restrict__ Qh, bf16* __restrict__ Kh, bf16* __restrict__ Vtt,
    float sq) {
  __shared__ bf16 As[128 * 64];   // 16KB, swizzled
  __shared__ bf16 Bs[128 * 64];
  const int tid = threadIdx.x;
  const int lane = tid & 63, wid = tid >> 6;
  const int wr = wid >> 1, wc = wid & 1;
  const int l15 = lane & 15, lhi = lane >> 4;
  const int tm = blockIdx.x * 128;
  const int by = blockIdx.y;
  const int seg = by / 6;                 // 0=Q 1=K 2=V
  const int tn = (by - seg * 6) * 128;

  const bf16* B = (seg == 0) ? Wqb : (seg == 1) ? Wkb : Wvb;
  const float* bias = (seg == 0) ? bq : (seg == 1) ? bk : bv;
  const float scale = (seg == 0) ? sq : 1.0f;
  const int K = 768;

  f32x4 zero = {0.f, 0.f, 0.f, 0.f};
  f32x4 acc[4][4];
  for (int i = 0; i < 4; ++i)
    for (int j = 0; j < 4; ++j) acc[i][j] = zero;

  for (int k0 = 0; k0 < K; k0 += 64) {
    __syncthreads();
    for (int it = 0; it < 4; ++it) {
      int o = (tid + it * 256) << 4;              // 0..16K-16
      int row = o >> 7, c = (o >> 4) & 7;
      int sw = swz_chunk(row, c) << 4;            // pre-swizzled source chunk
      gload_lds16((const char*)A + (((size_t)(tm + row) * K + k0) << 1) + sw, (char*)As + o);
      gload_lds16((const char*)B + (((size_t)(tn + row) * K + k0) << 1) + sw, (char*)Bs + o);
    }
    __syncthreads();
    for (int ks = 0; ks < 2; ++ks) {
      short8 af[4], bfr[4];
      for (int mi = 0; mi < 4; ++mi) {
        int row = wr * 64 + mi * 16 + l15;
        af[mi] = *(const short8*)((const char*)As + row * 128 +
                                  (swz_chunk(row, ks * 4 + lhi) << 4));
      }
      for (int ni = 0; ni < 4; ++ni) {
        int row = wc * 64 + ni * 16 + l15;
        bfr[ni] = *(const short8*)((const char*)Bs + row * 128 +
                                   (swz_chunk(row, ks * 4 + lhi) << 4));
      }
      for (int mi = 0; mi < 4; ++mi)
        for (int ni = 0; ni < 4; ++ni)
          acc[mi][ni] = MFMA16(af[mi], bfr[ni], acc[mi][ni]);
    }
  }

  if (seg == 2) {
    // V epilogue: tiled-VT layout, 4 consecutive tokens per ushort4
    for (int mi = 0; mi < 4; ++mi)
      for (int ni = 0; ni < 4; ++ni) {
        int m0 = tm + wr * 64 + mi * 16 + lhi * 4;     // tokens m0..m0+3
        int n = tn + wc * 64 + ni * 16 + l15;
        int b = m0 >> 12, s = m0 & 4095, hh = n >> 6, d = n & 63;
        float bia = bias[n];
        ushort4 us;
        us.x = f2bf(acc[mi][ni][0] + bia);
        us.y = f2bf(acc[mi][ni][1] + bia);
        us.z = f2bf(acc[mi][ni][2] + bia);
        us.w = f2bf(acc[mi][ni][3] + bia);
        size_t e = (size_t)(b * 12 + hh) * 262144 + (size_t)(s >> 6) * 4096 +
                   (size_t)((s >> 3) & 7) * 512 + d * 8 + (s & 7);
        *(ushort4*)(Vtt + e) = us;
      }
  } else {
    bf16* dst = (seg == 0) ? Qh : Kh;
    for (int mi = 0; mi < 4; ++mi)
      for (int ni = 0; ni < 4; ++ni)
        for (int j = 0; j < 4; ++j) {
          int m = tm + wr * 64 + mi * 16 + lhi * 4 + j;
          int n = tn + wc * 64 + ni * 16 + l15;
          float v = (acc[mi][ni][j] + bias[n]) * scale;
          int b = m >> 12, s = m & 4095, hh = n >> 6, d = n & 63;
          dst[(((size_t)(b * 12 + hh) * 4096 + s) << 6) + d] = __float2bfloat16(v);
        }
  }
}

// ------------------------------------------------------------ out-proj GEMM --
// 128x64 tiles, BK=64, swizzled LDS as above.
__global__ __launch_bounds__(256, 4) void gemm_wo(
    const bf16* __restrict__ A, const bf16* __restrict__ B,
    const float* __restrict__ bias, float* __restrict__ C) {
  __shared__ bf16 As[128 * 64];   // 16KB
  __shared__ bf16 Bs[64 * 64];    // 8KB
  const int tid = threadIdx.x;
  const int lane = tid & 63, wid = tid >> 6;
  const int l15 = lane & 15, lhi = lane >> 4;
  const int tm = blockIdx.x * 128, tn = blockIdx.y * 64;
  const int K = 768;

  f32x4 zero = {0.f, 0.f, 0.f, 0.f};
  f32x4 acc[2][4];
  for (int i = 0; i < 2; ++i)
    for (int j = 0; j < 4; ++j) acc[i][j] = zero;

  for (int k0 = 0; k0 < K; k0 += 64) {
    __syncthreads();
    for (int it = 0; it < 4; ++it) {
      int o = (tid + it * 256) << 4;
      int row = o >> 7, c = (o >> 4) & 7;
      int sw = swz_chunk(row, c) << 4;
      gload_lds16((const char*)A + (((size_t)(tm + row) * K + k0) << 1) + sw, (char*)As + o);
    }
    for (int it = 0; it < 2; ++it) {
      int o = (tid + it * 256) << 4;              // 0..8K-16
      int row = o >> 7, c = (o >> 4) & 7;
      int sw = swz_chunk(row, c) << 4;
      gload_lds16((const char*)B + (((size_t)(tn + row) * K + k0) << 1) + sw, (char*)Bs + o);
    }
    __syncthreads();
    for (int ks = 0; ks < 2; ++ks) {
      short8 af[2], bfr[4];
      for (int mi = 0; mi < 2; ++mi) {
        int row = wid * 32 + mi * 16 + l15;
        af[mi] = *(const short8*)((const char*)As + row * 128 +
                                  (swz_chunk(row, ks * 4 + lhi) << 4));
      }
      for (int ni = 0; ni < 4; ++ni) {
        int row = ni * 16 + l15;
        bfr[ni] = *(const short8*)((const char*)Bs + row * 128 +
                                   (swz_chunk(row, ks * 4 + lhi) << 4));
      }
      for (int mi = 0; mi < 2; ++mi)
        for (int ni = 0; ni < 4; ++ni)
          acc[mi][ni] = MFMA16(af[mi], bfr[ni], acc[mi][ni]);
    }
  }

  for (int mi = 0; mi < 2; ++mi)
    for (int ni = 0; ni < 4; ++ni)
      for (int j = 0; j < 4; ++j) {
        int m = tm + wid * 32 + mi * 16 + lhi * 4 + j;
        int n = tn + ni * 16 + l15;
        C[(size_t)m * 768 + n] = acc[mi][ni][j] + bias[n];
      }
}

// --------------------------------------------------------------- attention ---
// Round-13 best-verified structure (LDS-DMA double-buffer, one barrier/tile,
// XCD swizzle), V sourced from the tiled-VT layout: staging DMA reads chunk
// (c^(d&7), d) of the 8KB tile so the LDS image equals the swizzled V^T
// layout the PV frag-reads consume.
__global__ __launch_bounds__(256, 3) void attn_kernel(
    const bf16* __restrict__ Qh, const bf16* __restrict__ Kh,
    const bf16* __restrict__ VTT, bf16* __restrict__ AO) {
  __shared__ float4 smem4[34816 / 16];   // union: K/V bufs (32KB) | OX (34KB)
  char* smraw = (char*)smem4;
#define KT(b) (smraw + (b) * 8192)
#define VT(b) (smraw + 16384 + (b) * 8192)
  float* OX = (float*)smraw;             // [2 qsub][64 lane][68]

  const int tid = threadIdx.x;
  const int lane = tid & 63, wid = tid >> 6;
  const int l31 = lane & 31, h = lane >> 5;
  const int qsub = wid & 1, kvh = wid >> 1;

  // bijective XCD swizzle: all 32 q-tiles of a head on one XCD (3MB/XCD L2)
  const int i = blockIdx.x;
  const int xcd = i & 7, slot = i >> 3;
  const int bh = xcd * 3 + (slot >> 5);  // 0..23 = b*12+head
  const int qt = slot & 31;

  const size_t hb = (size_t)bh * 262144;       // 4096*64 elements per head
  const bf16* Qb = Qh + hb;
  const bf16* Kb = Kh + hb;
  const char* Vbc = (const char*)(VTT + hb);   // VT tile kt at +kt*8192 B
  const int qb = qt * 128 + qsub * 64;

  short8 qf[2][4];
#pragma unroll
  for (int j = 0; j < 2; ++j)
#pragma unroll
    for (int ki = 0; ki < 4; ++ki)
      qf[j][ki] = *(const short8*)((const char*)Qb + (size_t)(qb + 32 * j + l31) * 128 +
                                   ki * 32 + h * 16);

  f32x16 z16;
  for (int i2 = 0; i2 < 16; ++i2) z16[i2] = 0.f;
  f32x16 o00 = z16, o01 = z16, o10 = z16, o11 = z16;
  float psum0 = 0.f, psum1 = 0.f;

  const int krow = kvh * 32 + l31;

  // stage tile 0: K rows pre-swizzled; V chunks (c^(d&7), d) -> LDS (d, c)
  for (int it = 0; it < 2; ++it) {
    int o = (tid + it * 256) << 4;
    int row = o >> 7, c = (o >> 4) & 7;
    gload_lds16((const char*)Kb + row * 128 + (swz_chunk(row, c) << 4), KT(0) + o);
    gload_lds16(Vbc + (swz_chunk(row, c) << 10) + (row << 4), VT(0) + o);
  }
  __syncthreads();

  int cur = 0;
  for (int kt = 0; kt < 64; ++kt) {
    if (kt < 63) {
      const char* Kg = (const char*)(Kb + (size_t)(kt + 1) * 4096);
      const char* Vg = Vbc + (size_t)(kt + 1) * 8192;
      char* Kd = KT(cur ^ 1);
      char* Vd = VT(cur ^ 1);
      for (int it = 0; it < 2; ++it) {
        int o = (tid + it * 256) << 4;
        int row = o >> 7, c = (o >> 4) & 7;
        gload_lds16(Kg + row * 128 + (swz_chunk(row, c) << 4), Kd + o);
        gload_lds16(Vg + (swz_chunk(row, c) << 10) + (row << 4), Vd + o);
      }
    }

    const char* Kl = KT(cur);
    const char* Vl = VT(cur);

    f32x16 s0, s1;
    __builtin_amdgcn_s_setprio(1);
    {
      short8 kf = *(const short8*)(Kl + krow * 128 + (swz_chunk(krow, h) << 4));
      s0 = MFMA32(kf, qf[0][0], z16);
      s1 = MFMA32(kf, qf[1][0], z16);
    }
#pragma unroll
    for (int ki = 1; ki < 4; ++ki) {
      short8 kf = *(const short8*)(Kl + krow * 128 + (swz_chunk(krow, 2 * ki + h) << 4));
      s0 = MFMA32(kf, qf[0][ki], s0);
      s1 = MFMA32(kf, qf[1][ki], s1);
    }
    __builtin_amdgcn_s_setprio(0);

    short8 pb[2][2];
#pragma unroll
    for (int j = 0; j < 2; ++j) {
#pragma unroll
      for (int kk = 0; kk < 2; ++kk) {
        float p[8];
#pragma unroll
        for (int e = 0; e < 8; ++e)
          p[e] = __builtin_amdgcn_exp2f(j ? s1[8 * kk + e] : s0[8 * kk + e]);
        float ps = ((p[0] + p[1]) + (p[2] + p[3])) + ((p[4] + p[5]) + (p[6] + p[7]));
        if (j) psum1 += ps; else psum0 += ps;
        uint32_t A0 = cvtpk(p[0], p[1]), A1 = cvtpk(p[2], p[3]);
        uint32_t B0 = cvtpk(p[4], p[5]), B1 = cvtpk(p[6], p[7]);
        pl32swap(A0, B0);
        pl32swap(A1, B1);
        uint32_t w[4] = {A0, A1, B0, B1};
        short8 frag;
        __builtin_memcpy(&frag, w, 16);
        pb[j][kk] = frag;
      }
    }

    __builtin_amdgcn_s_setprio(1);
#pragma unroll
    for (int kk = 0; kk < 2; ++kk) {
      short8 v0 = *(const short8*)(Vl + l31 * 128 +
                                   (swz_chunk(l31, 4 * kvh + 2 * kk + h) << 4));
      short8 v1 = *(const short8*)(Vl + (32 + l31) * 128 +
                                   (swz_chunk(32 + l31, 4 * kvh + 2 * kk + h) << 4));
      o00 = MFMA32(v0, pb[0][kk], o00);
      o01 = MFMA32(v0, pb[1][kk], o01);
      o10 = MFMA32(v1, pb[0][kk], o10);
      o11 = MFMA32(v1, pb[1][kk], o11);
    }
    __builtin_amdgcn_s_setprio(0);

    __syncthreads();
    cur ^= 1;
  }

  psum0 += __shfl_xor(psum0, 32);
  psum1 += __shfl_xor(psum1, 32);

  float* W = OX + (size_t)(qsub * 64 + lane) * 68;
  if (kvh == 1) {
#pragma unroll
    for (int g = 0; g < 4; ++g) {
      *(float4*)(W + 0 * 16 + 4 * g) = make_float4(o00[4*g], o00[4*g+1], o00[4*g+2], o00[4*g+3]);
      *(float4*)(W + 1 * 16 + 4 * g) = make_float4(o01[4*g], o01[4*g+1], o01[4*g+2], o01[4*g+3]);
      *(float4*)(W + 2 * 16 + 4 * g) = make_float4(o10[4*g], o10[4*g+1], o10[4*g+2], o10[4*g+3]);
      *(float4*)(W + 3 * 16 + 4 * g) = make_float4(o11[4*g], o11[4*g+1], o11[4*g+2], o11[4*g+3]);
    }
    W[64] = psum0;
    W[65] = psum1;
  }
  __syncthreads();
  if (kvh == 0) {
#pragma unroll
    for (int g = 0; g < 4; ++g) {
      float4 a0 = *(const float4*)(W + 0 * 16 + 4 * g);
      float4 a1 = *(const float4*)(W + 1 * 16 + 4 * g);
      float4 a2 = *(const float4*)(W + 2 * 16 + 4 * g);
      float4 a3 = *(const float4*)(W + 3 * 16 + 4 * g);
      o00[4*g] += a0.x; o00[4*g+1] += a0.y; o00[4*g+2] += a0.z; o00[4*g+3] += a0.w;
      o01[4*g] += a1.x; o01[4*g+1] += a1.y; o01[4*g+2] += a1.z; o01[4*g+3] += a1.w;
      o10[4*g] += a2.x; o10[4*g+1] += a2.y; o10[4*g+2] += a2.z; o10[4*g+3] += a2.w;
      o11[4*g] += a3.x; o11[4*g+1] += a3.y; o11[4*g+2] += a3.z; o11[4*g+3] += a3.w;
    }
    psum0 += W[64];
    psum1 += W[65];
    float pinv0 = 1.0f / psum0;
    float pinv1 = 1.0f / psum1;

    const int b = bh / 12, hd = bh % 12;
#pragma unroll
    for (int j = 0; j < 2; ++j) {
      int q = qb + 32 * j + l31;
      char* base = (char*)AO + (((size_t)(b * 4096 + q)) * 768 + hd * 64) * 2;
      float pv = j ? pinv1 : pinv0;
#pragma unroll
      for (int t = 0; t < 2; ++t) {
#pragma unroll
        for (int u = 0; u < 4; ++u) {
          ushort4 us;
          float v0 = (t ? (j ? o11[4*u+0] : o10[4*u+0]) : (j ? o01[4*u+0] : o00[4*u+0]));
          float v1 = (t ? (j ? o11[4*u+1] : o10[4*u+1]) : (j ? o01[4*u+1] : o00[4*u+1]));
          float v2 = (t ? (j ? o11[4*u+2] : o10[4*u+2]) : (j ? o01[4*u+2] : o00[4*u+2]));
          float v3 = (t ? (j ? o11[4*u+3] : o10[4*u+3]) : (j ? o01[4*u+3] : o00[4*u+3]));
          us.x = f2bf(v0 * pv);
          us.y = f2bf(v1 * pv);
          us.z = f2bf(v2 * pv);
          us.w = f2bf(v3 * pv);
          int d0 = 32 * t + 8 * u + 4 * h;
          *(ushort4*)(base + d0 * 2) = us;
        }
      }
    }
  }
#undef KT
#undef VT
}

// ------------------------------------------------------------------ launch ---
extern "C" void kernel_launch(void* const* d_in, const int* in_sizes, int n_in,
                              void* d_out, int out_size, void* d_ws, size_t ws_size,
                              hipStream_t stream) {
  (void)in_sizes; (void)n_in; (void)out_size; (void)ws_size;
  const float* x  = (const float*)d_in[0];
  const float* Wq = (const float*)d_in[1];
  const float* bq = (const float*)d_in[2];
  const float* Wk = (const float*)d_in[3];
  const float* bk = (const float*)d_in[4];
  const float* Wv = (const float*)d_in[5];
  const float* bv = (const float*)d_in[6];
  const float* Wo = (const float*)d_in[7];
  const float* bo = (const float*)d_in[8];

  char* ws = (char*)d_ws;
  bf16* Qh  = (bf16*)(ws + 0);           // [24][4096][64]
  bf16* Kh  = (bf16*)(ws + 12582912);
  bf16* VTT = (bf16*)(ws + 25165824);    // tiled-VT [24][64][8][64][8]
  bf16* xb  = (bf16*)(ws + 37748736);    // x bf16; reused as AO after QKV GEMM
  bf16* Wqb = (bf16*)(ws + 50331648);
  bf16* Wkb = (bf16*)(ws + 51511296);
  bf16* Wvb = (bf16*)(ws + 52690944);
  bf16* Wob = (bf16*)(ws + 53870592);    // end ~55.05 MB
  bf16* AO  = xb;                        // attn out (xb dead after gemm_qkv)

  cvt_all<<<8448, 256, 0, stream>>>(x, Wq, Wk, Wv, Wo, xb, Wqb, Wkb, Wvb, Wob);

  const float SQ = 0.125f * 1.4426950408889634f;  // 1/sqrt(64) * log2(e)
  dim3 gq(64, 18);
  gemm_qkv<<<gq, 256, 0, stream>>>(xb, Wqb, Wkb, Wvb, bq, bk, bv,
                                   Qh, Kh, VTT, SQ);
  attn_kernel<<<768, 256, 0, stream>>>(Qh, Kh, VTT, AO);
  dim3 gw(64, 12);
  gemm_wo<<<gw, 256, 0, stream>>>(AO, Wob, bo, (float*)d_out);
}